// Round 4
// baseline (78.977 us; speedup 1.0000x reference)
//
#include <hip/hip_runtime.h>
#include <math.h>

// x = [32, 3, 512, 512] fp32. Output = concat(gabor flat, x flat), fp32.
constexpr int W_ = 512;
constexpr int H_ = 512;
constexpr int PLANE_ = W_ * H_;              // 262144
constexpr float S_ = 0.35355339059327373f;   // 1/(2*sqrt(2))
constexpr float PI_2 = 1.5707963267948966f;

typedef float f32x4 __attribute__((ext_vector_type(4)));

// atan(sqrt(s)/d) for s>=0, d>0, via rsq+rcp range reduction and a
// 2-FMA minimax polynomial (max err ~6e-4 rad; output budget is ~2 rad).
__device__ __forceinline__ float atan_mag(float s, float d)
{
    s = fmaxf(s, 1e-30f);                    // avoid 0*inf -> NaN
    float r  = __builtin_amdgcn_rsqf(s);     // 1/sqrt(s)
    float rd = __builtin_amdgcn_rcpf(d);     // 1/d
    float t  = s * r * rd;                   // sqrt(s)/d
    float it = d * r;                        // 1/t
    float tt = fminf(t, it);                 // reduce to [0,1]
    float u  = tt * tt;
    float p  = tt * fmaf(u, fmaf(u, 0.079331f, -0.288679f), 0.995354f);
    return (t > 1.0f) ? (PI_2 - p) : p;
}

// KX = [[-S,0,S],[-1,0,1],[-S,0,S]], KY = [[S,1,S],[0,0,0],[-S,-1,-S]]
// (XLA conv = cross-correlation, no flip). out = atan(mag)*(invstd/255) + a0.
__device__ __forceinline__ float gab(float tl, float tc, float tr,
                                     float ml, float mc, float mr,
                                     float bl, float bc, float br,
                                     float a1, float a0)
{
    float gx = fmaf(S_, (tr - tl) + (br - bl), mr - ml);
    float gy = fmaf(S_, (tl + tr) - (bl + br), tc - bc);
    float s  = fmaf(gx, gx, gy * gy);
    float den = mc + 0.001f;
    return fmaf(atan_mag(s, den), a1, a0);
}

// 8-wide x 2-row tile per thread; one wave spans a full 512-px row-pair,
// so left/right halos come from neighbor lanes via shuffle (borders are
// the true zero padding). Loads: exactly 8 coalesced dwordx4 per thread.
__global__ __launch_bounds__(256)
void gabor_kernel(const float* __restrict__ x,
                  float* __restrict__ gout,
                  float* __restrict__ xout)
{
    // XCD-bijective swizzle: 6144 blocks, 8 XCDs, 768 per XCD ->
    // each XCD owns a contiguous range of logical block ids (L2 locality
    // for vertically-shared halo rows).
    const int bid = (blockIdx.x & 7) * 768 + (blockIdx.x >> 3);

    const int lane  = threadIdx.x & 63;
    const int wv    = threadIdx.x >> 6;          // 0..3
    const int plane = bid >> 6;                  // 96 planes, 64 blocks/plane
    const int hp    = ((bid & 63) << 2) | wv;    // row-pair index 0..255
    const int h0    = hp << 1;                   // even output row
    const int w0    = lane << 3;                 // 8-wide chunk start

    const size_t pbase = (size_t)plane * PLANE_;
    const float* row0 = x + pbase + (size_t)h0 * W_ + w0;

    // rows: r0 = h0-1 (pad), r1 = h0, r2 = h0+1, r3 = h0+2 (pad)
    // [0]=left halo (shuffle), [1..8]=center 8, [9]=right halo (shuffle)
    float r0[10], r1[10], r2[10], r3[10];

#define LOADROW(dst, r)                                               \
    {                                                                 \
        f32x4 a = *reinterpret_cast<const f32x4*>(r);                 \
        f32x4 b = *reinterpret_cast<const f32x4*>((r) + 4);           \
        dst[1] = a.x; dst[2] = a.y; dst[3] = a.z; dst[4] = a.w;       \
        dst[5] = b.x; dst[6] = b.y; dst[7] = b.z; dst[8] = b.w;       \
    }
#define HALO(dst)                                                     \
    {                                                                 \
        float hl = __shfl_up(dst[8], 1, 64);                          \
        float hr = __shfl_down(dst[1], 1, 64);                        \
        dst[0] = (lane == 0)  ? 0.0f : hl;                            \
        dst[9] = (lane == 63) ? 0.0f : hr;                            \
    }

    LOADROW(r1, row0)
    LOADROW(r2, row0 + W_)
    if (h0 > 0) {                 // wave-uniform branch
        LOADROW(r0, row0 - W_)
    } else {
        #pragma unroll
        for (int i = 1; i <= 8; ++i) r0[i] = 0.0f;
    }
    if (h0 < H_ - 2) {            // wave-uniform branch
        LOADROW(r3, row0 + 2 * W_)
    } else {
        #pragma unroll
        for (int i = 1; i <= 8; ++i) r3[i] = 0.0f;
    }
    HALO(r1) HALO(r2) HALO(r0) HALO(r3)
#undef LOADROW
#undef HALO

    const int c = plane % 3;   // wave-uniform
    const float invstd = (c == 0) ? (1.0f/0.229f) : (c == 1 ? (1.0f/0.224f) : (1.0f/0.225f));
    const float mean   = (c == 0) ? 0.485f        : (c == 1 ? 0.456f        : 0.406f);
    const float a1 = invstd * (1.0f / 255.0f);
    const float a0 = -mean * invstd;

    float ga[8], gb[8];
    #pragma unroll
    for (int j = 1; j <= 8; ++j)
        ga[j-1] = gab(r0[j-1], r0[j], r0[j+1],
                      r1[j-1], r1[j], r1[j+1],
                      r2[j-1], r2[j], r2[j+1], a1, a0);
    #pragma unroll
    for (int j = 1; j <= 8; ++j)
        gb[j-1] = gab(r1[j-1], r1[j], r1[j+1],
                      r2[j-1], r2[j], r2[j+1],
                      r3[j-1], r3[j], r3[j+1], a1, a0);

    const size_t o0 = pbase + (size_t)h0 * W_ + w0;
    const size_t o1 = o0 + W_;

#define NTSTORE(p, a, b, cc, d)                                       \
    {                                                                 \
        f32x4 v_; v_.x = (a); v_.y = (b); v_.z = (cc); v_.w = (d);    \
        __builtin_nontemporal_store(v_, reinterpret_cast<f32x4*>(p)); \
    }
    NTSTORE(gout + o0,     ga[0], ga[1], ga[2], ga[3])
    NTSTORE(gout + o0 + 4, ga[4], ga[5], ga[6], ga[7])
    NTSTORE(gout + o1,     gb[0], gb[1], gb[2], gb[3])
    NTSTORE(gout + o1 + 4, gb[4], gb[5], gb[6], gb[7])
    NTSTORE(xout + o0,     r1[1], r1[2], r1[3], r1[4])
    NTSTORE(xout + o0 + 4, r1[5], r1[6], r1[7], r1[8])
    NTSTORE(xout + o1,     r2[1], r2[2], r2[3], r2[4])
    NTSTORE(xout + o1 + 4, r2[5], r2[6], r2[7], r2[8])
#undef NTSTORE
}

extern "C" void kernel_launch(void* const* d_in, const int* in_sizes, int n_in,
                              void* d_out, int out_size, void* d_ws, size_t ws_size,
                              hipStream_t stream) {
    const float* x = (const float*)d_in[0];
    float* out = (float*)d_out;
    const int n_elem = in_sizes[0];          // 25165824
    float* gout = out;
    float* xout = out + n_elem;

    const int grid = 96 * 64;                // 6144 blocks, 4 waves each
    gabor_kernel<<<grid, 256, 0, stream>>>(x, gout, xout);
}

// Round 5
// 66.619 us; speedup vs baseline: 1.1855x; 1.1855x over previous
//
#include <hip/hip_runtime.h>
#include <math.h>

// x = [32, 3, 512, 512] fp32. Output = concat(gabor flat, x flat), fp32.
constexpr int W_ = 512;
constexpr int H_ = 512;
constexpr int PLANE_ = W_ * H_;              // 262144
constexpr float S_ = 0.35355339059327373f;   // 1/(2*sqrt(2))
constexpr float PI_2 = 1.5707963267948966f;

typedef float f32x4 __attribute__((ext_vector_type(4)));

// atan(sqrt(s)/d) for s>=0, d>0, via rsq+rcp range reduction and a
// 2-FMA minimax polynomial (max err ~6e-4 rad; output budget is ~2 rad).
__device__ __forceinline__ float atan_mag(float s, float d)
{
    s = fmaxf(s, 1e-30f);                    // avoid 0*inf -> NaN
    float r  = __builtin_amdgcn_rsqf(s);     // 1/sqrt(s)
    float rd = __builtin_amdgcn_rcpf(d);     // 1/d
    float t  = s * r * rd;                   // sqrt(s)/d
    float it = d * r;                        // 1/t
    float tt = fminf(t, it);                 // reduce to [0,1]
    float u  = tt * tt;
    float p  = tt * fmaf(u, fmaf(u, 0.079331f, -0.288679f), 0.995354f);
    return (t > 1.0f) ? (PI_2 - p) : p;
}

// KX = [[-S,0,S],[-1,0,1],[-S,0,S]], KY = [[S,1,S],[0,0,0],[-S,-1,-S]]
// (XLA conv = cross-correlation, no flip). out = atan(mag)*a1 + a0.
__device__ __forceinline__ float gab(float tl, float tc, float tr,
                                     float ml, float mc, float mr,
                                     float bl, float bc, float br,
                                     float a1, float a0)
{
    float gx = fmaf(S_, (tr - tl) + (br - bl), mr - ml);
    float gy = fmaf(S_, (tl + tr) - (bl + br), tc - bc);
    float s  = fmaf(gx, gx, gy * gy);
    float den = mc + 0.001f;
    return fmaf(atan_mag(s, den), a1, a0);
}

// 8-wide x 2-row tile per thread (R3 structure: predicated scalar halo
// loads, natural block order). One wave spans a full 512-px row-pair.
__global__ __launch_bounds__(256)
void gabor_kernel(const float* __restrict__ x,
                  float* __restrict__ gout,
                  float* __restrict__ xout)
{
    const int lane  = threadIdx.x & 63;
    const int wv    = threadIdx.x >> 6;          // 0..3
    const int bid   = blockIdx.x;
    const int plane = bid >> 6;                  // 96 planes, 64 blocks/plane
    const int hp    = ((bid & 63) << 2) | wv;    // row-pair index 0..255
    const int h0    = hp << 1;                   // even output row
    const int w0    = lane << 3;                 // 8-wide chunk start

    const size_t pbase = (size_t)plane * PLANE_;
    const float* row0 = x + pbase + (size_t)h0 * W_ + w0;

    // rows: r0 = h0-1 (pad), r1 = h0, r2 = h0+1, r3 = h0+2 (pad)
    // [0]=left halo, [1..8]=center 8, [9]=right halo
    float r0[10], r1[10], r2[10], r3[10];

#define LOADROW(dst, r)                                               \
    {                                                                 \
        f32x4 a = *reinterpret_cast<const f32x4*>(r);                 \
        f32x4 b = *reinterpret_cast<const f32x4*>((r) + 4);           \
        dst[1] = a.x; dst[2] = a.y; dst[3] = a.z; dst[4] = a.w;       \
        dst[5] = b.x; dst[6] = b.y; dst[7] = b.z; dst[8] = b.w;       \
        dst[0] = (lane > 0)  ? (r)[-1] : 0.0f;                        \
        dst[9] = (lane < 63) ? (r)[8]  : 0.0f;                        \
    }

    LOADROW(r1, row0)
    LOADROW(r2, row0 + W_)
    if (h0 > 0) {                 // wave-uniform branch
        LOADROW(r0, row0 - W_)
    } else {
        #pragma unroll
        for (int i = 0; i < 10; ++i) r0[i] = 0.0f;
    }
    if (h0 < H_ - 2) {            // wave-uniform branch
        LOADROW(r3, row0 + 2 * W_)
    } else {
        #pragma unroll
        for (int i = 0; i < 10; ++i) r3[i] = 0.0f;
    }
#undef LOADROW

    const int c = plane % 3;   // wave-uniform
    const float invstd = (c == 0) ? (1.0f/0.229f) : (c == 1 ? (1.0f/0.224f) : (1.0f/0.225f));
    const float mean   = (c == 0) ? 0.485f        : (c == 1 ? 0.456f        : 0.406f);
    const float a1 = invstd * (1.0f / 255.0f);
    const float a0 = -mean * invstd;

    float ga[8], gb[8];
    #pragma unroll
    for (int j = 1; j <= 8; ++j)
        ga[j-1] = gab(r0[j-1], r0[j], r0[j+1],
                      r1[j-1], r1[j], r1[j+1],
                      r2[j-1], r2[j], r2[j+1], a1, a0);
    #pragma unroll
    for (int j = 1; j <= 8; ++j)
        gb[j-1] = gab(r1[j-1], r1[j], r1[j+1],
                      r2[j-1], r2[j], r2[j+1],
                      r3[j-1], r3[j], r3[j+1], a1, a0);

    const size_t o0 = pbase + (size_t)h0 * W_ + w0;
    const size_t o1 = o0 + W_;

#define NTSTORE(p, a, b, cc, d)                                       \
    {                                                                 \
        f32x4 v_; v_.x = (a); v_.y = (b); v_.z = (cc); v_.w = (d);    \
        __builtin_nontemporal_store(v_, reinterpret_cast<f32x4*>(p)); \
    }
    NTSTORE(gout + o0,     ga[0], ga[1], ga[2], ga[3])
    NTSTORE(gout + o0 + 4, ga[4], ga[5], ga[6], ga[7])
    NTSTORE(gout + o1,     gb[0], gb[1], gb[2], gb[3])
    NTSTORE(gout + o1 + 4, gb[4], gb[5], gb[6], gb[7])
    NTSTORE(xout + o0,     r1[1], r1[2], r1[3], r1[4])
    NTSTORE(xout + o0 + 4, r1[5], r1[6], r1[7], r1[8])
    NTSTORE(xout + o1,     r2[1], r2[2], r2[3], r2[4])
    NTSTORE(xout + o1 + 4, r2[5], r2[6], r2[7], r2[8])
#undef NTSTORE
}

extern "C" void kernel_launch(void* const* d_in, const int* in_sizes, int n_in,
                              void* d_out, int out_size, void* d_ws, size_t ws_size,
                              hipStream_t stream) {
    const float* x = (const float*)d_in[0];
    float* out = (float*)d_out;
    const int n_elem = in_sizes[0];          // 25165824
    float* gout = out;
    float* xout = out + n_elem;

    const int grid = 96 * 64;                // 6144 blocks, 4 waves each
    gabor_kernel<<<grid, 256, 0, stream>>>(x, gout, xout);
}